// Round 11
// baseline (488.517 us; speedup 1.0000x reference)
//
#include <hip/hip_runtime.h>
#include <cstdint>
#include <cstddef>

// C[4096,4096] = sum_r input[r] @ weight[r]^T  == GEMM M=N=4096, K=8192, fp32 out.
// Phase 1: fp32 -> bf16 cast, R0 version (~80us real; dur_us carries ~170us of
//          fixed non-kernel overhead — cast is near its roofline).
// Phase 2: R15: even-read 8-phase GEMM, CORRECT ledger. R14 failed because
//          A-halves are read at P0 AND P2 (wave groups wm2=0/1) and B-halves
//          at every b0R/b1R read (hb groups) — its VM12 ledger let P4 read
//          unlanded buf.A1. R15 keeps R6's PROVEN stage slots + phase shape
//          (224us, clean absmax x4 runs) and moves ONLY the b0R reads:
//          prologue b0R(t0); P3 b0R(t1); P7 b0R(t2); P0/P4 aR-only ->
//          8/4/8/4 reads/phase. Deadlines (group-correct): B-halves(tau)
//          retire before P3/P7-top b0R(tau); A-halves before P4/P0-top
//          aR(tau) => VM6 at P2,P3,P6,P7 ends. Queue walk verified:
//          [B0,A0,B1](t1)=6 -> P2-end retires them (publ. P2 end-BAR, covers
//          P3 b0R + P4 A0) -> P3-end retires A1(t1) (covers P4 aR) ->
//          symmetric P6/P7. WAR unchanged from R6.

#define M_DIM 4096
#define N_DIM 4096
#define K_DIM 8192
#define K_LOCAL 1024
#define RANKS 8
#define NT 128  // K-tiles: RANKS * (K_LOCAL/64)

typedef __bf16 bf16x8 __attribute__((ext_vector_type(8)));
typedef float f32x4 __attribute__((ext_vector_type(4)));

__device__ __forceinline__ unsigned short f2bf(float f) {
    unsigned int u = __float_as_uint(f);
    unsigned int r = (u + 0x7fffu + ((u >> 16) & 1u)) >> 16;
    return (unsigned short)r;
}

// ---------- Phase 1: linear fp32 -> bf16 cast (R0 version) ----------
__global__ __launch_bounds__(256) void convert_cast(
    const float* __restrict__ srcA, unsigned short* __restrict__ dstA,
    const float* __restrict__ srcB, unsigned short* __restrict__ dstB,
    int blocks_per_tensor) {
    const float* src = srcA;
    unsigned short* dst = dstA;
    int b = blockIdx.x;
    if (b >= blocks_per_tensor) { b -= blocks_per_tensor; src = srcB; dst = dstB; }
    size_t base = (size_t)b * 4096 + threadIdx.x * 4;
#pragma unroll
    for (int i = 0; i < 4; ++i) {
        size_t e = base + i * 1024;
        f32x4 v = __builtin_nontemporal_load((const f32x4*)(src + e));
        ushort4 o;
        o.x = f2bf(v.x); o.y = f2bf(v.y); o.z = f2bf(v.z); o.w = f2bf(v.w);
        *(ushort4*)(dst + e) = o;
    }
}

// ---------- Phase 2: 256^2 even-read 8-phase bf16 MFMA GEMM ----------
__device__ __forceinline__ void async_copy16(const unsigned short* g, unsigned short* l) {
    __builtin_amdgcn_global_load_lds(
        (const __attribute__((address_space(1))) void*)g,
        (__attribute__((address_space(3))) void*)l,
        16, 0, 0);
}

#define VM6()   asm volatile("s_waitcnt vmcnt(6)" ::: "memory")
#define VM0()   asm volatile("s_waitcnt vmcnt(0)" ::: "memory")
#define BAR()   __builtin_amdgcn_s_barrier()

__global__ __launch_bounds__(512, 2) void gemm_bf16(
    const unsigned short* __restrict__ A,  // [R, M, K_LOCAL] bf16
    const unsigned short* __restrict__ B,  // [R, N, K_LOCAL] bf16
    float* __restrict__ C) {               // [M, N] fp32
    // Per-tensor-half regions: [buf][rowhalf][128 rows][64 k] (128B rows).
    // 16B chunk c of row r stored at chunk c ^ (r & 7) (0 conflicts, R3-R13).
    __shared__ __align__(16) unsigned short As[2][2][128][64];
    __shared__ __align__(16) unsigned short Bs[2][2][128][64];

    const int tid = threadIdx.x;   // 0..511
    const int lane = tid & 63;
    const int wave = tid >> 6;     // 0..7
    const int l15 = lane & 15;
    const int l4 = lane >> 4;      // 0..3
    const int wm2 = wave >> 2;     // 0..1 -> row block *128 (= A half read)
    const int wn4 = wave & 3;      // 0..3 -> col block *64

    // Bijective XCD swizzle: 256 blocks, each XCD owns a 4x8 tile sub-grid.
    const int bid = blockIdx.x;
    const int xcd = bid & 7;
    const int idx = bid >> 3;                       // 0..31
    const int trow = (xcd >> 1) * 4 + (idx >> 3);   // 0..15
    const int tcol = (xcd & 1) * 8 + (idx & 7);     // 0..15
    const int bm0 = trow * 256;
    const int bn0 = tcol * 256;

    // Stage unit = one tensor-half: 128 rows x 64 k x 2B = 16KB = 1024 chunks;
    // li = i*512 + tid: row = li>>3, cpos = li&7, global chunk g = cpos^(row&7).
    const unsigned short* gA[2];
    const unsigned short* gB[2];
    int lo[2];
#pragma unroll
    for (int i = 0; i < 2; ++i) {
        int li = i * 512 + tid;
        int row = li >> 3;
        int g = (li & 7) ^ (row & 7);
        gA[i] = A + (size_t)(bm0 + row) * K_LOCAL + g * 8;
        gB[i] = B + (size_t)(bn0 + row) * K_LOCAL + g * 8;
        lo[i] = li * 8;  // ushort units
    }

    auto stageA = [&](int t, int buf, int h) {
        const size_t off = (size_t)(t >> 4) * ((size_t)M_DIM * K_LOCAL)
                         + (size_t)((t & 15) << 6) + (size_t)h * (128 * K_LOCAL);
        unsigned short* l = &As[buf][h][0][0];
        async_copy16(gA[0] + off, l + lo[0]);
        async_copy16(gA[1] + off, l + lo[1]);
    };
    auto stageB = [&](int t, int buf, int h) {
        const size_t off = (size_t)(t >> 4) * ((size_t)M_DIM * K_LOCAL)
                         + (size_t)((t & 15) << 6) + (size_t)h * (128 * K_LOCAL);
        unsigned short* l = &Bs[buf][h][0][0];
        async_copy16(gB[0] + off, l + lo[0]);
        async_copy16(gB[1] + off, l + lo[1]);
    };

    // Fragment reads: k-chunk c = ks*4 + l4 stored at c ^ (row&7); frag rows
    // are <mult of 16> + l15, so row&7 == l15&7.
    const int swzk0 = ((l4 + 0) ^ (l15 & 7)) * 8;  // ks = 0
    const int swzk1 = ((l4 + 4) ^ (l15 & 7)) * 8;  // ks = 1
    const int hb = wn4 >> 1;                        // B half for this wave
    const int brow_base = (wn4 & 1) * 64 + l15;     // B row within half

    f32x4 acc[8][4] = {};
    bf16x8 aR[8], a1R[8], b0R[4], b1R[4];

    auto LDA = [&](bf16x8* dst, int buf, int mh) {
#pragma unroll
        for (int m = 0; m < 4; ++m) {
            const unsigned short* rp = &As[buf][wm2][mh * 64 + m * 16 + l15][0];
            dst[m * 2 + 0] = *(const bf16x8*)(rp + swzk0);
            dst[m * 2 + 1] = *(const bf16x8*)(rp + swzk1);
        }
    };
    auto LDB = [&](bf16x8* dst, int buf, int nh) {
#pragma unroll
        for (int n = 0; n < 2; ++n) {
            const unsigned short* rp = &Bs[buf][hb][brow_base + nh * 32 + n * 16][0];
            dst[n * 2 + 0] = *(const bf16x8*)(rp + swzk0);
            dst[n * 2 + 1] = *(const bf16x8*)(rp + swzk1);
        }
    };
    auto MFMA16 = [&](const bf16x8* a, const bf16x8* b, int mh, int nh) {
        __builtin_amdgcn_s_setprio(1);
#pragma unroll
        for (int m = 0; m < 4; ++m)
#pragma unroll
            for (int n = 0; n < 2; ++n)
#pragma unroll
                for (int ks = 0; ks < 2; ++ks)
                    acc[mh * 4 + m][nh * 2 + n] = __builtin_amdgcn_mfma_f32_16x16x32_bf16(
                        a[m * 2 + ks], b[n * 2 + ks], acc[mh * 4 + m][nh * 2 + n], 0, 0, 0);
        __builtin_amdgcn_s_setprio(0);
    };

    // Prologue: t0 all 4 units (8 loads), then B0/A0/B1 of t1 (6 loads).
    // VM6 retires exactly t0's 8; publication by BAR; then read b0R(t0)
    // (needs both B-halves of t0 — landed). Consumed at P0's MFMA.
    stageA(0, 0, 0); stageA(0, 0, 1); stageB(0, 0, 0); stageB(0, 0, 1);
    stageB(1, 1, 0); stageA(1, 1, 0); stageB(1, 1, 1);
    VM6(); BAR();
    LDB(b0R, 0, 0);   // b0R(t0)

    // Reads 8/4/8/4 per phase; stage slots = R6; VM6 at P2/P3/P6/P7 ends.
    for (int i = 0; i < NT / 2; ++i) {
        const int t1 = 2 * i + 1;
        const int t2 = (2 * i + 2) & (NT - 1);
        const int t3 = (2 * i + 3) & (NT - 1);
        // P0: Q00(t) | read aR(t) | stage A1(t1)->buf1.A1 [last read prev P6]
        LDA(aR, 0, 0); stageA(t1, 1, 1);
        BAR(); MFMA16(aR, b0R, 0, 0); BAR();
        // P1: Q01(t) | read b1R(t) | stage B0(t2)->buf0.B0 [b0R(t) drained P0]
        LDB(b1R, 0, 1); stageB(t2, 0, 0);
        BAR(); MFMA16(aR, b1R, 0, 1); BAR();
        // P2: Q10(t) | read a1R(t) | stage A0(t2)->buf0.A0 | VM6: retire
        //     B0/A0/B1(t1) -> covers P3's b0R(t1) + P4's A0(t1)
        LDA(a1R, 0, 1); stageA(t2, 0, 0);
        BAR(); MFMA16(a1R, b0R, 1, 0); VM6(); BAR();
        // P3: Q11(t) | read b0R(t1)<-buf1 [B-halves(t1) retired P2-end] |
        //     stage B1(t2)->buf0.B1 | VM6: retire A1(t1) -> covers P4's aR
        LDB(b0R, 1, 0); stageB(t2, 0, 1);
        BAR(); MFMA16(a1R, b1R, 1, 1); VM6(); BAR();
        // P4: Q00(t1) | read aR(t1) [A-halves(t1) retired P2/P3] |
        //     stage A1(t2)->buf0.A1 [last read P2]
        LDA(aR, 1, 0); stageA(t2, 0, 1);
        BAR(); MFMA16(aR, b0R, 0, 0); BAR();
        // P5: Q01(t1) | read b1R(t1) | stage B0(t3)->buf1.B0 [b0R(t1) drained P4]
        LDB(b1R, 1, 1); stageB(t3, 1, 0);
        BAR(); MFMA16(aR, b1R, 0, 1); BAR();
        // P6: Q10(t1) | read a1R(t1) | stage A0(t3)->buf1.A0 | VM6: retire
        //     B0/A0/B1(t2) -> covers P7's b0R(t2) + next-P0's A0(t2)
        LDA(a1R, 1, 1); stageA(t3, 1, 0);
        BAR(); MFMA16(a1R, b0R, 1, 0); VM6(); BAR();
        // P7: Q11(t1) | read b0R(t2)<-buf0 [B-halves(t2) retired P6-end] |
        //     stage B1(t3)->buf1.B1 | VM6: retire A1(t2) -> covers next-P0 aR
        LDB(b0R, 0, 0); stageB(t3, 1, 1);
        BAR(); MFMA16(a1R, b1R, 1, 1); VM6(); BAR();
    }
    VM0();  // drain outstanding DMA (incl. dead wrap-stages) before exit

    // Epilogue: C/D layout col = lane&15, row = (lane>>4)*4 + reg.
#pragma unroll
    for (int m = 0; m < 8; ++m) {
        int row0 = bm0 + wm2 * 128 + m * 16 + l4 * 4;
#pragma unroll
        for (int n = 0; n < 4; ++n) {
            int col = bn0 + wn4 * 64 + n * 16 + l15;
#pragma unroll
            for (int rr = 0; rr < 4; ++rr)
                C[(size_t)(row0 + rr) * N_DIM + col] = acc[m][n][rr];
        }
    }
}

// ---------- Fallback (ws too small): naive fp32 tiled GEMM ----------
__global__ void gemm_naive(const float* __restrict__ A, const float* __restrict__ B,
                           float* __restrict__ C) {
    __shared__ float As[16][17];
    __shared__ float Bs[16][17];
    int tx = threadIdx.x, ty = threadIdx.y;
    int m = blockIdx.y * 16 + ty;
    int n0 = blockIdx.x * 16;
    float accv = 0.f;
    for (int kt = 0; kt < K_DIM; kt += 16) {
        int r = kt >> 10;
        int k = (kt & 1023) + tx;
        As[ty][tx] = A[((size_t)r * M_DIM + m) * K_LOCAL + k];
        Bs[ty][tx] = B[((size_t)r * N_DIM + (n0 + ty)) * K_LOCAL + k];
        __syncthreads();
#pragma unroll
        for (int kk = 0; kk < 16; ++kk) accv += As[ty][kk] * Bs[tx][kk];
        __syncthreads();
    }
    C[(size_t)m * N_DIM + n0 + tx] = accv;
}

extern "C" void kernel_launch(void* const* d_in, const int* in_sizes, int n_in,
                              void* d_out, int out_size, void* d_ws, size_t ws_size,
                              hipStream_t stream) {
    const float* inp = (const float*)d_in[0];
    const float* wgt = (const float*)d_in[1];
    float* out = (float*)d_out;

    const size_t elems = (size_t)M_DIM * K_DIM;              // 33,554,432 per tensor
    const size_t need = 2 * elems * sizeof(unsigned short);  // 128 MiB

    if (ws_size >= need) {
        unsigned short* Abf = (unsigned short*)d_ws;
        unsigned short* Bbf = Abf + elems;
        const int bpt = (int)(elems / 4096);      // 8192 blocks per tensor
        convert_cast<<<bpt * 2, 256, 0, stream>>>(inp, Abf, wgt, Bbf, bpt);
        gemm_bf16<<<256, 512, 0, stream>>>(Abf, Bbf, out);
    } else {
        dim3 grid(N_DIM / 16, M_DIM / 16);
        dim3 block(16, 16);
        gemm_naive<<<grid, block, 0, stream>>>(inp, wgt, out);
    }
}

// Round 12
// 466.297 us; speedup vs baseline: 1.0477x; 1.0477x over previous
//
#include <hip/hip_runtime.h>
#include <cstdint>
#include <cstddef>

// C[4096,4096] = sum_r input[r] @ weight[r]^T  == GEMM M=N=4096, K=8192, fp32 out.
// Phase 1: fp32 -> bf16 cast, R0 version (~80us real; dur_us carries ~170us of
//          fixed non-kernel overhead — cast is near its roofline).
// Phase 2: R16 = R13 (226us twin of best R6) with the MID-PHASE s_barrier
//          replaced by sched_barrier(0): compile-time issue-order fence
//          (keeps {reads; stage-DMA} BEFORE the MFMA cluster — R8's mistake
//          was moving stage AFTER MFMA), zero runtime cost. Tests the
//          ~200cyc/barrier theory cleanly: 8 runtime barriers/tile-pair
//          removed. Landing guarantees unchanged (phase-END VM6->BAR pairs:
//          P3-end retires t1 fully, P7-end retires t2 fully). Max wave skew
//          1 phase; tightest WAR (P0-read buf0.B0 vs P1-stage) covered by
//          DMA's >=200cyc L2 fetch vs ds_read ~120cyc completion.
//          (R15 even-read: 244us, falsified, reverted. R14: broken ledger.
//          R8 stage-late: 268us. R7 fusion: 376us. R5 read-ahead: spills.)

#define M_DIM 4096
#define N_DIM 4096
#define K_DIM 8192
#define K_LOCAL 1024
#define RANKS 8
#define NT 128  // K-tiles: RANKS * (K_LOCAL/64)

typedef __bf16 bf16x8 __attribute__((ext_vector_type(8)));
typedef float f32x4 __attribute__((ext_vector_type(4)));

__device__ __forceinline__ unsigned short f2bf(float f) {
    unsigned int u = __float_as_uint(f);
    unsigned int r = (u + 0x7fffu + ((u >> 16) & 1u)) >> 16;
    return (unsigned short)r;
}

// ---------- Phase 1: linear fp32 -> bf16 cast (R0 version) ----------
__global__ __launch_bounds__(256) void convert_cast(
    const float* __restrict__ srcA, unsigned short* __restrict__ dstA,
    const float* __restrict__ srcB, unsigned short* __restrict__ dstB,
    int blocks_per_tensor) {
    const float* src = srcA;
    unsigned short* dst = dstA;
    int b = blockIdx.x;
    if (b >= blocks_per_tensor) { b -= blocks_per_tensor; src = srcB; dst = dstB; }
    size_t base = (size_t)b * 4096 + threadIdx.x * 4;
#pragma unroll
    for (int i = 0; i < 4; ++i) {
        size_t e = base + i * 1024;
        f32x4 v = __builtin_nontemporal_load((const f32x4*)(src + e));
        ushort4 o;
        o.x = f2bf(v.x); o.y = f2bf(v.y); o.z = f2bf(v.z); o.w = f2bf(v.w);
        *(ushort4*)(dst + e) = o;
    }
}

// ---------- Phase 2: 256^2 deep-prefetch 8-phase bf16 MFMA GEMM ----------
__device__ __forceinline__ void async_copy16(const unsigned short* g, unsigned short* l) {
    __builtin_amdgcn_global_load_lds(
        (const __attribute__((address_space(1))) void*)g,
        (__attribute__((address_space(3))) void*)l,
        16, 0, 0);
}

#define VM6()   asm volatile("s_waitcnt vmcnt(6)" ::: "memory")
#define VM0()   asm volatile("s_waitcnt vmcnt(0)" ::: "memory")
#define BAR()   __builtin_amdgcn_s_barrier()
#define SCHED0() __builtin_amdgcn_sched_barrier(0)

__global__ __launch_bounds__(512, 2) void gemm_bf16(
    const unsigned short* __restrict__ A,  // [R, M, K_LOCAL] bf16
    const unsigned short* __restrict__ B,  // [R, N, K_LOCAL] bf16
    float* __restrict__ C) {               // [M, N] fp32
    // Per-tensor-half regions: [buf][rowhalf][128 rows][64 k] (128B rows).
    // 16B chunk c of row r stored at chunk c ^ (r & 7) (0 conflicts, R3-R15).
    __shared__ __align__(16) unsigned short As[2][2][128][64];
    __shared__ __align__(16) unsigned short Bs[2][2][128][64];

    const int tid = threadIdx.x;   // 0..511
    const int lane = tid & 63;
    const int wave = tid >> 6;     // 0..7
    const int l15 = lane & 15;
    const int l4 = lane >> 4;      // 0..3
    const int wm2 = wave >> 2;     // 0..1 -> row block *128 (= A half read)
    const int wn4 = wave & 3;      // 0..3 -> col block *64

    // Bijective XCD swizzle: 256 blocks, each XCD owns a 4x8 tile sub-grid.
    const int bid = blockIdx.x;
    const int xcd = bid & 7;
    const int idx = bid >> 3;                       // 0..31
    const int trow = (xcd >> 1) * 4 + (idx >> 3);   // 0..15
    const int tcol = (xcd & 1) * 8 + (idx & 7);     // 0..15
    const int bm0 = trow * 256;
    const int bn0 = tcol * 256;

    // Stage unit = one tensor-half: 128 rows x 64 k x 2B = 16KB = 1024 chunks;
    // li = i*512 + tid: row = li>>3, cpos = li&7, global chunk g = cpos^(row&7).
    const unsigned short* gA[2];
    const unsigned short* gB[2];
    int lo[2];
#pragma unroll
    for (int i = 0; i < 2; ++i) {
        int li = i * 512 + tid;
        int row = li >> 3;
        int g = (li & 7) ^ (row & 7);
        gA[i] = A + (size_t)(bm0 + row) * K_LOCAL + g * 8;
        gB[i] = B + (size_t)(bn0 + row) * K_LOCAL + g * 8;
        lo[i] = li * 8;  // ushort units
    }

    auto stageA = [&](int t, int buf, int h) {
        const size_t off = (size_t)(t >> 4) * ((size_t)M_DIM * K_LOCAL)
                         + (size_t)((t & 15) << 6) + (size_t)h * (128 * K_LOCAL);
        unsigned short* l = &As[buf][h][0][0];
        async_copy16(gA[0] + off, l + lo[0]);
        async_copy16(gA[1] + off, l + lo[1]);
    };
    auto stageB = [&](int t, int buf, int h) {
        const size_t off = (size_t)(t >> 4) * ((size_t)M_DIM * K_LOCAL)
                         + (size_t)((t & 15) << 6) + (size_t)h * (128 * K_LOCAL);
        unsigned short* l = &Bs[buf][h][0][0];
        async_copy16(gB[0] + off, l + lo[0]);
        async_copy16(gB[1] + off, l + lo[1]);
    };

    // Fragment reads: k-chunk c = ks*4 + l4 stored at c ^ (row&7); frag rows
    // are <mult of 16> + l15, so row&7 == l15&7.
    const int swzk0 = ((l4 + 0) ^ (l15 & 7)) * 8;  // ks = 0
    const int swzk1 = ((l4 + 4) ^ (l15 & 7)) * 8;  // ks = 1
    const int hb = wn4 >> 1;                        // B half for this wave
    const int brow_base = (wn4 & 1) * 64 + l15;     // B row within half

    f32x4 acc[8][4] = {};
    bf16x8 aR[8], a1R[8], b0R[4], b1R[4];

    auto LDA = [&](bf16x8* dst, int buf, int mh) {
#pragma unroll
        for (int m = 0; m < 4; ++m) {
            const unsigned short* rp = &As[buf][wm2][mh * 64 + m * 16 + l15][0];
            dst[m * 2 + 0] = *(const bf16x8*)(rp + swzk0);
            dst[m * 2 + 1] = *(const bf16x8*)(rp + swzk1);
        }
    };
    auto LDB = [&](bf16x8* dst, int buf, int nh) {
#pragma unroll
        for (int n = 0; n < 2; ++n) {
            const unsigned short* rp = &Bs[buf][hb][brow_base + nh * 32 + n * 16][0];
            dst[n * 2 + 0] = *(const bf16x8*)(rp + swzk0);
            dst[n * 2 + 1] = *(const bf16x8*)(rp + swzk1);
        }
    };
    auto MFMA16 = [&](const bf16x8* a, const bf16x8* b, int mh, int nh) {
        __builtin_amdgcn_s_setprio(1);
#pragma unroll
        for (int m = 0; m < 4; ++m)
#pragma unroll
            for (int n = 0; n < 2; ++n)
#pragma unroll
                for (int ks = 0; ks < 2; ++ks)
                    acc[mh * 4 + m][nh * 2 + n] = __builtin_amdgcn_mfma_f32_16x16x32_bf16(
                        a[m * 2 + ks], b[n * 2 + ks], acc[mh * 4 + m][nh * 2 + n], 0, 0, 0);
        __builtin_amdgcn_s_setprio(0);
    };

    // Prologue: t0 all 4 units (8 loads), then B0/A0/B1 of t1 (6 loads).
    // VM6 retires exactly t0's 8; {B0,A0,B1}(t1) stay in flight.
    stageA(0, 0, 0); stageA(0, 0, 1); stageB(0, 0, 0); stageB(0, 0, 1);
    stageB(1, 1, 0); stageA(1, 1, 0); stageB(1, 1, 1);
    VM6(); BAR();

    // Per phase: {reads; stage; SCHED0; MFMA16; [VM6]; BAR}. SCHED0 pins the
    // issue order (stage-DMA early) at zero runtime cost; the single runtime
    // barrier per phase carries all cross-wave publication.
    for (int i = 0; i < NT / 2; ++i) {
        const int t1 = 2 * i + 1;
        const int t2 = (2 * i + 2) & (NT - 1);
        const int t3 = (2 * i + 3) & (NT - 1);
        // P0: Q00(t) | stage A1(t1)  [buf1.A1 read last at prev P6]
        LDA(aR, 0, 0); LDB(b0R, 0, 0); stageA(t1, 1, 1);
        SCHED0(); MFMA16(aR, b0R, 0, 0); BAR();
        // P1: Q01(t) | stage B0(t2)  [buf0.B0 read at P0]
        LDB(b1R, 0, 1); stageB(t2, 0, 0);
        SCHED0(); MFMA16(aR, b1R, 0, 1); BAR();
        // P2: Q10(t) | stage A0(t2)  [buf0.A0 read at P0]
        LDA(a1R, 0, 1); stageA(t2, 0, 0);
        SCHED0(); MFMA16(a1R, b0R, 1, 0); BAR();
        // P3: Q11(t) | stage B1(t2)  [buf0.B1 read at P1] | vmcnt(6): t1 lands
        stageB(t2, 0, 1);
        SCHED0(); MFMA16(a1R, b1R, 1, 1); VM6(); BAR();
        // P4: Q00(t1) | stage A1(t2) [buf0.A1 read at P2]
        LDA(aR, 1, 0); LDB(b0R, 1, 0); stageA(t2, 0, 1);
        SCHED0(); MFMA16(aR, b0R, 0, 0); BAR();
        // P5: Q01(t1) | stage B0(t3) [buf1.B0 read at P4]
        LDB(b1R, 1, 1); stageB(t3, 1, 0);
        SCHED0(); MFMA16(aR, b1R, 0, 1); BAR();
        // P6: Q10(t1) | stage A0(t3) [buf1.A0 read at P4]
        LDA(a1R, 1, 1); stageA(t3, 1, 0);
        SCHED0(); MFMA16(a1R, b0R, 1, 0); BAR();
        // P7: Q11(t1) | stage B1(t3) [buf1.B1 read at P5] | vmcnt(6): t2 lands
        stageB(t3, 1, 1);
        SCHED0(); MFMA16(a1R, b1R, 1, 1); VM6(); BAR();
    }
    VM0();  // drain outstanding DMA before exit

    // Epilogue: C/D layout col = lane&15, row = (lane>>4)*4 + reg.
#pragma unroll
    for (int m = 0; m < 8; ++m) {
        int row0 = bm0 + wm2 * 128 + m * 16 + l4 * 4;
#pragma unroll
        for (int n = 0; n < 4; ++n) {
            int col = bn0 + wn4 * 64 + n * 16 + l15;
#pragma unroll
            for (int rr = 0; rr < 4; ++rr)
                C[(size_t)(row0 + rr) * N_DIM + col] = acc[m][n][rr];
        }
    }
}

// ---------- Fallback (ws too small): naive fp32 tiled GEMM ----------
__global__ void gemm_naive(const float* __restrict__ A, const float* __restrict__ B,
                           float* __restrict__ C) {
    __shared__ float As[16][17];
    __shared__ float Bs[16][17];
    int tx = threadIdx.x, ty = threadIdx.y;
    int m = blockIdx.y * 16 + ty;
    int n0 = blockIdx.x * 16;
    float accv = 0.f;
    for (int kt = 0; kt < K_DIM; kt += 16) {
        int r = kt >> 10;
        int k = (kt & 1023) + tx;
        As[ty][tx] = A[((size_t)r * M_DIM + m) * K_LOCAL + k];
        Bs[ty][tx] = B[((size_t)r * N_DIM + (n0 + ty)) * K_LOCAL + k];
        __syncthreads();
#pragma unroll
        for (int kk = 0; kk < 16; ++kk) accv += As[ty][kk] * Bs[tx][kk];
        __syncthreads();
    }
    C[(size_t)m * N_DIM + n0 + tx] = accv;
}

extern "C" void kernel_launch(void* const* d_in, const int* in_sizes, int n_in,
                              void* d_out, int out_size, void* d_ws, size_t ws_size,
                              hipStream_t stream) {
    const float* inp = (const float*)d_in[0];
    const float* wgt = (const float*)d_in[1];
    float* out = (float*)d_out;

    const size_t elems = (size_t)M_DIM * K_DIM;              // 33,554,432 per tensor
    const size_t need = 2 * elems * sizeof(unsigned short);  // 128 MiB

    if (ws_size >= need) {
        unsigned short* Abf = (unsigned short*)d_ws;
        unsigned short* Bbf = Abf + elems;
        const int bpt = (int)(elems / 4096);      // 8192 blocks per tensor
        convert_cast<<<bpt * 2, 256, 0, stream>>>(inp, Abf, wgt, Bbf, bpt);
        gemm_bf16<<<256, 512, 0, stream>>>(Abf, Bbf, out);
    } else {
        dim3 grid(N_DIM / 16, M_DIM / 16);
        dim3 block(16, 16);
        gemm_naive<<<grid, block, 0, stream>>>(inp, wgt, out);
    }
}